// Round 5
// baseline (212.129 us; speedup 1.0000x reference)
//
#include <hip/hip_runtime.h>
#include <math.h>

// Density loss: B=8, N=2048, C=3, K=16 (self-distance 0 included).
// R5: 256-thread blocks (4 waves), 4 points/wave, grid 2048 (8 blocks/CU
//   worth, LDS caps 4 co-resident -> 16 waves/CU, 2x oversubscribed).
//   launch_bounds(256,4): VGPR cap 128 -- NO forced spill (R4's bug was
//   (512,8) -> 32 VGPRs -> 43 MB scratch writes).
//   Staged pts carry |x|^2 in .w; track d~ = |xj|^2 - 2 xi.xj (ordering
//   invariant per point), add 16*|xi|^2 at the end. Per lane per point:
//   sorted 4-slot min-list. thr = 16th smallest of 32 pair-mins (R2-validated
//   bitonic32 on pair-duplicated lanes, 16 swizzle rounds). Counts via
//   ballot/popcount. sum16 = qualifier sum - (cnt-16) largest (butterfly-max
//   rounds). Overflow or cnt>44 -> exact streaming extraction.
// Kernel 2: 1 block reduces 2048 block-partials -> scalar MSE.

#define NPTS 2048

// Exact fallback: 16 rounds of global min-extraction with lexicographic
// (value, candidate-index) keys; re-reads LDS each round. True distances.
__device__ __attribute__((noinline)) float exact_stream(
    const float4* __restrict__ pts, float px, float py, float pz, int lane) {
  float lastV = -INFINITY;
  int lastI = -1;
  float s = 0.f;
  for (int r = 0; r < 16; ++r) {
    float bv = INFINITY;
    int bi = 0x7fffffff;
    #pragma unroll
    for (int m = 0; m < 32; ++m) {
      float4 c = pts[lane + (m << 6)];
      float dx = px - c.x, dy = py - c.y, dz = pz - c.z;
      float d = fmaf(dz, dz, fmaf(dy, dy, dx * dx));
      int idx = (m << 6) | lane;
      bool gt = (d > lastV) || (d == lastV && idx > lastI);
      bool better = gt && ((d < bv) || (d == bv && idx < bi));
      bv = better ? d : bv;
      bi = better ? idx : bi;
    }
    #pragma unroll
    for (int ofs = 1; ofs < 64; ofs <<= 1) {
      float ov = __shfl_xor(bv, ofs);
      int oi = __shfl_xor(bi, ofs);
      bool take = (ov < bv) || (ov == bv && oi < bi);
      bv = take ? ov : bv;
      bi = take ? oi : bi;
    }
    s += bv;
    lastV = bv;
    lastI = bi;
  }
  return s;
}

__global__ __launch_bounds__(256, 4) void knn_kernel(
    const float* __restrict__ seed, const float* __restrict__ gt,
    float* __restrict__ out_partial) {
  __shared__ float4 pts[NPTS];  // 32 KB
  __shared__ float wsum[4];

  const int bid = blockIdx.x;    // 2048 = 2*8*128
  const int t = bid >> 10;       // tensor
  const int b = (bid >> 7) & 7;  // batch
  const int g = bid & 127;       // group of 16 points
  const float* base = (t == 0 ? seed : gt) + b * (NPTS * 3);
  const int tid = threadIdx.x;

  // Stage 2048 points; consecutive-lane b128 writes (conflict-free).
  #pragma unroll
  for (int r = 0; r < 8; ++r) {
    int p = tid + (r << 8);
    float x = base[3 * p], y = base[3 * p + 1], z = base[3 * p + 2];
    float w = fmaf(z, z, fmaf(y, y, x * x));  // |xj|^2
    pts[p] = make_float4(x, y, z, w);
  }
  __syncthreads();

  const int wave = tid >> 6, lane = tid & 63;
  const int i0 = (g << 4) + (wave << 2);

  float px[4], py[4], pz[4];
  #pragma unroll
  for (int j = 0; j < 4; ++j) {
    float4 q = pts[i0 + j];
    px[j] = q.x; py[j] = q.y; pz[j] = q.z;
  }

  // Sorted 4 smallest d~ per lane per point (ascending s0..s3).
  float s0[4], s1[4], s2[4], s3[4];
  #pragma unroll
  for (int j = 0; j < 4; ++j) s0[j] = s1[j] = s2[j] = s3[j] = INFINITY;

  #pragma unroll 8
  for (int m = 0; m < 32; ++m) {
    float4 c = pts[lane + (m << 6)];
    #pragma unroll
    for (int j = 0; j < 4; ++j) {
      float dot = fmaf(pz[j], c.z, fmaf(py[j], c.y, px[j] * c.x));
      float d = fmaf(-2.f, dot, c.w);  // d~ = |xj|^2 - 2 xi.xj
      float u;
      u = fminf(s0[j], d); d = fmaxf(s0[j], d); s0[j] = u;
      u = fminf(s1[j], d); d = fmaxf(s1[j], d); s1[j] = u;
      u = fminf(s2[j], d); d = fmaxf(s2[j], d); s2[j] = u;
      s3[j] = fminf(s3[j], d);
    }
  }

  // thr[j] = 16th smallest of 32 pair-mins (valid upper bound on v16).
  // Pair-min then bitonic32 over logical index p = lane>>1 (R2-validated).
  float v0 = fminf(s0[0], __shfl_xor(s0[0], 1));
  float v1 = fminf(s0[1], __shfl_xor(s0[1], 1));
  float v2 = fminf(s0[2], __shfl_xor(s0[2], 1));
  float v3 = fminf(s0[3], __shfl_xor(s0[3], 1));
  const int p = lane >> 1;
  #pragma unroll
  for (int k = 2; k <= 32; k <<= 1) {
    #pragma unroll
    for (int j = k >> 1; j > 0; j >>= 1) {
      bool keepmin = ((p & j) == 0) != ((p & k) != 0);
      float o0 = __shfl_xor(v0, j << 1), o1 = __shfl_xor(v1, j << 1);
      float o2 = __shfl_xor(v2, j << 1), o3 = __shfl_xor(v3, j << 1);
      v0 = keepmin ? fminf(v0, o0) : fmaxf(v0, o0);
      v1 = keepmin ? fminf(v1, o1) : fmaxf(v1, o1);
      v2 = keepmin ? fminf(v2, o2) : fmaxf(v2, o2);
      v3 = keepmin ? fminf(v3, o3) : fmaxf(v3, o3);
    }
  }
  const float thr[4] = {__shfl(v0, 30), __shfl(v1, 30), __shfl(v2, 30),
                        __shfl(v3, 30)};

  // Qualifier counts via ballot/popcount (scalar pipe); sums via butterfly.
  int cnt[4];
  unsigned long long bad[4];
  float sq[4];
  #pragma unroll
  for (int j = 0; j < 4; ++j) {
    bool q0 = s0[j] <= thr[j], q1 = s1[j] <= thr[j];
    bool q2 = s2[j] <= thr[j], q3 = s3[j] <= thr[j];
    unsigned long long b3 = __ballot(q3);
    bad[j] = b3;  // lane may hold >= 4 qualifiers -> possible drop
    cnt[j] = __popcll(__ballot(q0)) + __popcll(__ballot(q1)) +
             __popcll(__ballot(q2)) + __popcll(b3);
    sq[j] = (q0 ? s0[j] : 0.f) + (q1 ? s1[j] : 0.f) +
            (q2 ? s2[j] : 0.f) + (q3 ? s3[j] : 0.f);
  }
  #pragma unroll
  for (int ofs = 1; ofs < 64; ofs <<= 1) {
    #pragma unroll
    for (int j = 0; j < 4; ++j) sq[j] += __shfl_xor(sq[j], ofs);
  }

  float out[4];
  #pragma unroll
  for (int j = 0; j < 4; ++j) {
    if (bad[j] != 0ull || cnt[j] > 44) {  // wave-uniform, rare
      out[j] = exact_stream(pts, px[j], py[j], pz[j], lane);
    } else {
      float a0 = s0[j], a1 = s1[j], a2 = s2[j], a3 = s3[j];
      const float T = thr[j];
      float S = sq[j];
      const int r = cnt[j] - 16;  // wave-uniform, >= 0
      for (int q = 0; q < r; ++q) {
        float lm = -INFINITY;
        lm = (a0 <= T) ? fmaxf(lm, a0) : lm;
        lm = (a1 <= T) ? fmaxf(lm, a1) : lm;
        lm = (a2 <= T) ? fmaxf(lm, a2) : lm;
        lm = (a3 <= T) ? fmaxf(lm, a3) : lm;
        float bv = lm;
        #pragma unroll
        for (int ofs = 1; ofs < 64; ofs <<= 1) bv = fmaxf(bv, __shfl_xor(bv, ofs));
        S -= bv;
        int owner = __builtin_ctzll(__ballot(lm == bv));
        if (lane == owner) {  // retire one instance
          if (a3 == bv) a3 = INFINITY;
          else if (a2 == bv) a2 = INFINITY;
          else if (a1 == bv) a1 = INFINITY;
          else a0 = INFINITY;
        }
      }
      float sqi = fmaf(pz[j], pz[j], fmaf(py[j], py[j], px[j] * px[j]));
      out[j] = S + 16.f * sqi;  // undo the per-point additive shift
    }
  }

  // Block partial: sum of this block's 16 point-sums.
  float wtot = out[0] + out[1] + out[2] + out[3];  // lane-uniform
  if (lane == 0) wsum[wave] = wtot;
  __syncthreads();
  if (tid == 0)
    out_partial[bid] = wsum[0] + wsum[1] + wsum[2] + wsum[3];
}

__global__ __launch_bounds__(1024) void final_kernel(
    const float* __restrict__ part, float* __restrict__ out) {
  __shared__ float acc[16];
  const int tid = threadIdx.x;  // 1024
  const int wave = tid >> 6, lane = tid & 63;
  // wave w reduces segment (t*8+b) == w: 128 partials.
  float v = part[(wave << 7) + lane] + part[(wave << 7) + 64 + lane];
  #pragma unroll
  for (int ofs = 1; ofs < 64; ofs <<= 1) v += __shfl_xor(v, ofs);
  if (lane == 0) acc[wave] = v;
  __syncthreads();
  if (tid == 0) {
    const float scale = 1.f / (2048.f * 16.f);
    float a = 0.f;
    #pragma unroll
    for (int bb = 0; bb < 8; ++bb) {
      float diff = (acc[bb] - acc[8 + bb]) * scale;
      a += diff * diff;
    }
    out[0] = a * 0.125f;
  }
}

extern "C" void kernel_launch(void* const* d_in, const int* in_sizes, int n_in,
                              void* d_out, int out_size, void* d_ws, size_t ws_size,
                              hipStream_t stream) {
  const float* seed = (const float*)d_in[0];
  const float* gt = (const float*)d_in[1];
  float* out = (float*)d_out;
  float* ws = (float*)d_ws;  // 2048 floats used

  knn_kernel<<<2048, 256, 0, stream>>>(seed, gt, ws);
  final_kernel<<<1, 1024, 0, stream>>>(ws, out);
}

// Round 6
// 140.047 us; speedup vs baseline: 1.5147x; 1.5147x over previous
//
#include <hip/hip_runtime.h>
#include <math.h>

// Density loss: B=8, N=2048, C=3, K=16 (self-distance 0 included).
// R6: wave-per-point (32768 waves, 1024-thr blocks = best structure, R1) with
//   swizzle-free selection. Per lane: sorted 5-slot min-list over its 32
//   candidates (d~ = |xj|^2 - 2 xi.xj shift trick). Floats -> order-preserving
//   uint keys; binary search for exact 16th-smallest key via ballot+popcount
//   (zero DS ops, no serial swizzle chains). sum16 = sum(key<v16) +
//   (16-c_lt)*v16, + 16|xi|^2 shift. ballot(k4<=v16k) exactly catches any
//   case where a hidden (6th+) per-lane value could be <= v16 (P~3e-4/pt)
//   -> exact_stream fallback (R3-proven).
// Kernel 2: 1 block reduces 2048 block-partials -> scalar MSE.

#define NPTS 2048

__device__ __forceinline__ unsigned f2key(float f) {
  unsigned u = __float_as_uint(f);
  return u ^ ((unsigned)((int)u >> 31) | 0x80000000u);
}
__device__ __forceinline__ float key2f(unsigned k) {
  unsigned u = (k & 0x80000000u) ? (k ^ 0x80000000u) : ~k;
  return __uint_as_float(u);
}

// Exact fallback: 16 rounds of global min-extraction with lexicographic
// (value, candidate-index) keys; re-reads LDS each round. True distances.
__device__ __attribute__((noinline)) float exact_stream(
    const float4* __restrict__ pts, float px, float py, float pz, int lane) {
  float lastV = -INFINITY;
  int lastI = -1;
  float s = 0.f;
  for (int r = 0; r < 16; ++r) {
    float bv = INFINITY;
    int bi = 0x7fffffff;
    #pragma unroll
    for (int m = 0; m < 32; ++m) {
      float4 c = pts[lane + (m << 6)];
      float dx = px - c.x, dy = py - c.y, dz = pz - c.z;
      float d = fmaf(dz, dz, fmaf(dy, dy, dx * dx));
      int idx = (m << 6) | lane;
      bool gt = (d > lastV) || (d == lastV && idx > lastI);
      bool better = gt && ((d < bv) || (d == bv && idx < bi));
      bv = better ? d : bv;
      bi = better ? idx : bi;
    }
    #pragma unroll
    for (int ofs = 1; ofs < 64; ofs <<= 1) {
      float ov = __shfl_xor(bv, ofs);
      int oi = __shfl_xor(bi, ofs);
      bool take = (ov < bv) || (ov == bv && oi < bi);
      bv = take ? ov : bv;
      bi = take ? oi : bi;
    }
    s += bv;
    lastV = bv;
    lastI = bi;
  }
  return s;
}

__global__ __launch_bounds__(1024) void knn_kernel(
    const float* __restrict__ seed, const float* __restrict__ gt,
    float* __restrict__ out_partial) {
  __shared__ float4 pts[NPTS];  // 32 KB
  __shared__ float wsum[16];

  const int bid = blockIdx.x;    // 2048 = 2*8*128
  const int t = bid >> 10;       // tensor
  const int b = (bid >> 7) & 7;  // batch
  const int g = bid & 127;       // group of 16 points
  const float* base = (t == 0 ? seed : gt) + b * (NPTS * 3);
  const int tid = threadIdx.x;

  // Stage 2048 points (|x|^2 in .w); consecutive b128 writes (conflict-free).
  #pragma unroll
  for (int r = 0; r < 2; ++r) {
    int p = tid + (r << 10);
    float x = base[3 * p], y = base[3 * p + 1], z = base[3 * p + 2];
    pts[p] = make_float4(x, y, z, fmaf(z, z, fmaf(y, y, x * x)));
  }
  __syncthreads();

  const int wave = tid >> 6, lane = tid & 63;
  const int i = (g << 4) + wave;  // this wave's point
  const float4 q = pts[i];
  const float px = q.x, py = q.y, pz = q.z;

  // Per-lane sorted 5 smallest d~ over the lane's 32 candidates.
  float s0 = INFINITY, s1 = INFINITY, s2 = INFINITY, s3 = INFINITY,
        s4 = INFINITY;
  #pragma unroll
  for (int m = 0; m < 32; ++m) {
    float4 c = pts[lane + (m << 6)];
    float dot = fmaf(pz, c.z, fmaf(py, c.y, px * c.x));
    float d = fmaf(-2.f, dot, c.w);  // d~ = |xj|^2 - 2 xi.xj
    float u;
    u = fminf(s0, d); d = fmaxf(s0, d); s0 = u;
    u = fminf(s1, d); d = fmaxf(s1, d); s1 = u;
    u = fminf(s2, d); d = fmaxf(s2, d); s2 = u;
    u = fminf(s3, d); d = fmaxf(s3, d); s3 = u;
    s4 = fminf(s4, d);
  }

  const unsigned k0 = f2key(s0), k1 = f2key(s1), k2 = f2key(s2),
                 k3 = f2key(s3), k4 = f2key(s4);

  // Search bounds: [global min, max lane-min]. v16 lies within (the 16th
  // smallest is <= the 16th-smallest lane-min <= max lane-min).
  unsigned lo = k0, hi = k0;
  #pragma unroll
  for (int ofs = 1; ofs < 64; ofs <<= 1) {
    unsigned ol = (unsigned)__shfl_xor((int)lo, ofs);
    unsigned oh = (unsigned)__shfl_xor((int)hi, ofs);
    lo = lo < ol ? lo : ol;
    hi = hi > oh ? hi : oh;
  }
  unsigned slo = (unsigned)__builtin_amdgcn_readfirstlane((int)lo);
  unsigned shi = (unsigned)__builtin_amdgcn_readfirstlane((int)hi);

  // Smallest key T with count(keys <= T) >= 16 (counts over slots; any
  // undercount from hidden 6th+ values is caught by the k4 check below).
  while (slo < shi) {
    unsigned mid = slo + ((shi - slo) >> 1);
    int c = __popcll(__ballot(k0 <= mid)) + __popcll(__ballot(k1 <= mid)) +
            __popcll(__ballot(k2 <= mid)) + __popcll(__ballot(k3 <= mid)) +
            __popcll(__ballot(k4 <= mid));
    if (c >= 16) shi = mid; else slo = mid + 1;
  }
  const unsigned v16k = slo;

  float out_pt;
  if (__ballot(k4 <= v16k) != 0ull) {  // possible hidden value <= v16: exact
    out_pt = exact_stream(pts, px, py, pz, lane);
  } else {
    int clt = __popcll(__ballot(k0 < v16k)) + __popcll(__ballot(k1 < v16k)) +
              __popcll(__ballot(k2 < v16k)) + __popcll(__ballot(k3 < v16k));
    float sl = (k0 < v16k ? s0 : 0.f) + (k1 < v16k ? s1 : 0.f) +
               (k2 < v16k ? s2 : 0.f) + (k3 < v16k ? s3 : 0.f);
    #pragma unroll
    for (int ofs = 1; ofs < 64; ofs <<= 1) sl += __shfl_xor(sl, ofs);
    const float v16 = key2f(v16k);
    const float sqi = fmaf(pz, pz, fmaf(py, py, px * px));
    out_pt = sl + (float)(16 - clt) * v16 + 16.f * sqi;  // undo shift
  }

  if (lane == 0) wsum[wave] = out_pt;
  __syncthreads();
  if (wave == 0) {
    float v = (lane < 16) ? wsum[lane] : 0.f;
    #pragma unroll
    for (int ofs = 1; ofs < 64; ofs <<= 1) v += __shfl_xor(v, ofs);
    if (lane == 0) out_partial[bid] = v;
  }
}

__global__ __launch_bounds__(1024) void final_kernel(
    const float* __restrict__ part, float* __restrict__ out) {
  __shared__ float acc[16];
  const int tid = threadIdx.x;  // 1024
  const int wave = tid >> 6, lane = tid & 63;
  // wave w reduces segment (t*8+b) == w: 128 partials.
  float v = part[(wave << 7) + lane] + part[(wave << 7) + 64 + lane];
  #pragma unroll
  for (int ofs = 1; ofs < 64; ofs <<= 1) v += __shfl_xor(v, ofs);
  if (lane == 0) acc[wave] = v;
  __syncthreads();
  if (tid == 0) {
    const float scale = 1.f / (2048.f * 16.f);
    float a = 0.f;
    #pragma unroll
    for (int bb = 0; bb < 8; ++bb) {
      float diff = (acc[bb] - acc[8 + bb]) * scale;
      a += diff * diff;
    }
    out[0] = a * 0.125f;
  }
}

extern "C" void kernel_launch(void* const* d_in, const int* in_sizes, int n_in,
                              void* d_out, int out_size, void* d_ws, size_t ws_size,
                              hipStream_t stream) {
  const float* seed = (const float*)d_in[0];
  const float* gt = (const float*)d_in[1];
  float* out = (float*)d_out;
  float* ws = (float*)d_ws;  // 2048 floats used

  knn_kernel<<<2048, 1024, 0, stream>>>(seed, gt, ws);
  final_kernel<<<1, 1024, 0, stream>>>(ws, out);
}